// Round 14
// baseline (482.125 us; speedup 1.0000x reference)
//
#include <hip/hip_runtime.h>
#include <stdint.h>

#define B_SZ  32
#define T_SZ  2048
#define IN_D  128
#define HID   512
#define NCHAIN 410              // ceil(T/5)
#define INV_TAUX 0.005f         // 1/200

typedef __attribute__((ext_vector_type(8))) short bf16x8;
typedef __attribute__((ext_vector_type(4))) float f32x4;
typedef __attribute__((ext_vector_type(4))) float float4v;
typedef __attribute__((ext_vector_type(4))) unsigned short u16x4;
typedef __attribute__((ext_vector_type(8))) unsigned short u16x8;

// Operands SWAPPED: mfma(b, a) => D^T. Lane holds row = frag_m*16 + (lane&15),
// cols = frag_n*16 + (lane>>4)*4 + q (4 consecutive) -> vectorized epilogues.
#define MFMA(b, a, c) __builtin_amdgcn_mfma_f32_16x16x32_bf16((b), (a), (c), 0, 0, 0)

__device__ __forceinline__ unsigned short f2bf(float x) {
  union { float f; unsigned int u; } v; v.f = x;
  unsigned int r = v.u + 0x7FFFu + ((v.u >> 16) & 1u);  // RNE
  return (unsigned short)(r >> 16);
}
__device__ __forceinline__ float bf2f(unsigned short b) {
  union { unsigned int u; float f; } v; v.u = ((unsigned int)b) << 16;
  return v.f;
}
__device__ __forceinline__ float fast_tanh(float x) {
  float ax = fabsf(x);
  float e = __expf(-2.0f * ax);
  float r = (1.0f - e) * __builtin_amdgcn_rcpf(1.0f + e);
  return x < 0.0f ? -r : r;
}
__device__ __forceinline__ void gload_lds16(const void* g, void* l) {
  __builtin_amdgcn_global_load_lds(
      reinterpret_cast<__attribute__((address_space(1))) void*>(reinterpret_cast<uintptr_t>(g)),
      reinterpret_cast<__attribute__((address_space(3))) void*>(reinterpret_cast<uintptr_t>(l)),
      16, 0, 0);
}

// ---------------------------------------------------------------------------
// Weights FRAGMENT-LINEAR (see prep_k). 1m x 8n wave layout.
// ROUND-14: 4-deep B-prefetch pipeline (prefetch distance 3 ~= 600+ cy) in all
// nk=16 GEMM phases -- depth-1 dbuf left each kk-half stalled on L2 latency
// (enc5: MfmaUtil 24 / VALU 35 / HBM 8 -> latency-serialized, not pipe-bound).
// Named buffers bA..bD + fully-unrolled kk (static idx); WAR enforces schedule.
// ---------------------------------------------------------------------------

template<int LSTR, int MF>
__device__ __forceinline__ void phase16(
    const unsigned short* __restrict__ bl, int nfb,
    const unsigned short* sbuf, int lrow, int lhi, int sw,
    f32x4 (&acc)[MF][4])
{
  auto ld = [&](bf16x8 (&dst)[4], int kkv) {
#pragma unroll
    for (int n = 0; n < 4; ++n)
      dst[n] = *(const bf16x8*)(bl + ((nfb + (n << 4) + kkv) << 9));
  };
  auto cmp = [&](bf16x8 (&buf)[4], int kkv) {
    const int c = (kkv << 2) + lhi;
    const int slot = (c & ~7) | ((c & 7) ^ sw);
    bf16x8 af[MF];
#pragma unroll
    for (int m = 0; m < MF; ++m)
      af[m] = *(const bf16x8*)(sbuf + (m * 16 + lrow) * LSTR + (slot << 3));
#pragma unroll
    for (int n = 0; n < 4; ++n)
#pragma unroll
      for (int m = 0; m < MF; ++m)
        acc[m][n] = MFMA(buf[n], af[m], acc[m][n]);
  };
  bf16x8 bA[4], bB[4], bC[4], bD[4];
  ld(bA, 0); ld(bB, 1); ld(bC, 2);
  ld(bD, 3);  cmp(bA, 0);
  ld(bA, 4);  cmp(bB, 1);
  ld(bB, 5);  cmp(bC, 2);
  ld(bC, 6);  cmp(bD, 3);
  ld(bD, 7);  cmp(bA, 4);
  ld(bA, 8);  cmp(bB, 5);
  ld(bB, 9);  cmp(bC, 6);
  ld(bC, 10); cmp(bD, 7);
  ld(bD, 11); cmp(bA, 8);
  ld(bA, 12); cmp(bB, 9);
  ld(bB, 13); cmp(bC, 10);
  ld(bC, 14); cmp(bD, 11);
  ld(bD, 15); cmp(bA, 12);
  cmp(bB, 13); cmp(bC, 14); cmp(bD, 15);
}

// N=1-fragment variant (decoder layer 2), same 4-deep pipeline
__device__ __forceinline__ void phase16_n1(
    const unsigned short* __restrict__ bl, int nfb,
    const unsigned short* sbuf, int lrow, int lhi, int sw,
    f32x4 (&acc2)[4])
{
  auto ld = [&](bf16x8& dst, int kkv) {
    dst = *(const bf16x8*)(bl + ((nfb + kkv) << 9));
  };
  auto cmp = [&](bf16x8& buf, int kkv) {
    const int c = (kkv << 2) + lhi;
    const int slot = (c & ~7) | ((c & 7) ^ sw);
#pragma unroll
    for (int m = 0; m < 4; ++m) {
      bf16x8 af = *(const bf16x8*)(sbuf + ((m * 16 + lrow) << 9) + (slot << 3));
      acc2[m] = MFMA(buf, af, acc2[m]);
    }
  };
  bf16x8 c0, c1, c2, c3;
  ld(c0, 0); ld(c1, 1); ld(c2, 2);
  ld(c3, 3);  cmp(c0, 0);
  ld(c0, 4);  cmp(c1, 1);
  ld(c1, 5);  cmp(c2, 2);
  ld(c2, 6);  cmp(c3, 3);
  ld(c3, 7);  cmp(c0, 4);
  ld(c0, 8);  cmp(c1, 5);
  ld(c1, 9);  cmp(c2, 6);
  ld(c2, 10); cmp(c3, 7);
  ld(c3, 11); cmp(c0, 8);
  ld(c0, 12); cmp(c1, 9);
  ld(c1, 13); cmp(c2, 10);
  ld(c2, 14); cmp(c3, 11);
  ld(c3, 15); cmp(c0, 12);
  cmp(c1, 13); cmp(c2, 14); cmp(c3, 15);
}

// ---------------------------------------------------------------------------
// enc5: 3 encoder layers + xseq dump + 2 recon-decoder layers, one kernel.
// ---------------------------------------------------------------------------
__global__ __launch_bounds__(512) void enc5_k(
    const float* __restrict__ in_seq,
    const unsigned short* __restrict__ wt,
    const float* __restrict__ be1, const float* __restrict__ be2,
    const float* __restrict__ be3,
    const unsigned short* __restrict__ Wd1t,
    const unsigned short* __restrict__ Wd2t,
    const float* __restrict__ bd1, const float* __restrict__ bd2,
    unsigned short* __restrict__ xseq,
    float* __restrict__ outr)
{
  __shared__ __attribute__((aligned(16))) unsigned short sH[64 * 512];  // 64 KB
  unsigned short* sA = sH;   // alias: input tile (64x128) in sH's head

  const int tid = threadIdx.x;
  const int m0 = blockIdx.x * 64;
  const int wave = tid >> 6, lane = tid & 63;
  const int wn = wave;
  const int lrow = lane & 15, lhi = lane >> 4, sw = lrow & 7;

  // stage input tile f32 -> bf16, chunk-swizzled
#pragma unroll
  for (int p = 0; p < 2; ++p) {
    int id = (p << 9) + tid;
    int row = id >> 4, cc = id & 15;
    const float* src = in_seq + (size_t)(m0 + row) * IN_D + (cc << 3);
    float4v u0 = *(const float4v*)src;
    float4v u1 = *(const float4v*)(src + 4);
    u16x8 h;
    h[0] = f2bf(u0[0]); h[1] = f2bf(u0[1]); h[2] = f2bf(u0[2]); h[3] = f2bf(u0[3]);
    h[4] = f2bf(u1[0]); h[5] = f2bf(u1[1]); h[6] = f2bf(u1[2]); h[7] = f2bf(u1[3]);
    int slot = (cc & 8) | ((cc & 7) ^ (row & 7));
    *(u16x8*)(sA + (row << 7) + (slot << 3)) = h;
  }
  __syncthreads();

  f32x4 acc[4][4];

  auto epi = [&](const float* bias) {
    __syncthreads();
#pragma unroll
    for (int n = 0; n < 4; ++n) {
      const int col0 = (wn << 6) + n * 16 + (lhi << 2);
      const float4v bv = *(const float4v*)(bias + col0);
      const int c2 = col0 >> 3;
#pragma unroll
      for (int m = 0; m < 4; ++m) {
        const int row = m * 16 + lrow;
        const int slot2 = (c2 & ~7) | ((c2 & 7) ^ (row & 7));
        u16x4 h;
#pragma unroll
        for (int q = 0; q < 4; ++q) h[q] = f2bf(fast_tanh(acc[m][n][q] + bv[q]));
        *(u16x4*)(sH + (row << 9) + (slot2 << 3) + (col0 & 7)) = h;
      }
    }
    __syncthreads();
  };

  // ---- encoder layer 0: K=128 (nk=4), all-preload ----
  {
#pragma unroll
    for (int m = 0; m < 4; ++m)
#pragma unroll
      for (int n = 0; n < 4; ++n) acc[m][n] = (f32x4){0.f, 0.f, 0.f, 0.f};
    const unsigned short* bl = wt + (lane << 3);
    const int nfb = (wn << 2) * 4;
    bf16x8 b0[4], b1[4], b2[4], b3[4];
#pragma unroll
    for (int n = 0; n < 4; ++n) {
      b0[n] = *(const bf16x8*)(bl + ((nfb + n * 4 + 0) << 9));
      b1[n] = *(const bf16x8*)(bl + ((nfb + n * 4 + 1) << 9));
      b2[n] = *(const bf16x8*)(bl + ((nfb + n * 4 + 2) << 9));
      b3[n] = *(const bf16x8*)(bl + ((nfb + n * 4 + 3) << 9));
    }
    auto cmp0 = [&](bf16x8 (&buf)[4], int kkv) {
      const int c = (kkv << 2) + lhi;
      const int slot = (c & ~7) | ((c & 7) ^ sw);
      bf16x8 af[4];
#pragma unroll
      for (int m = 0; m < 4; ++m)
        af[m] = *(const bf16x8*)(sH + (m * 16 + lrow) * 128 + (slot << 3));
#pragma unroll
      for (int n = 0; n < 4; ++n)
#pragma unroll
        for (int m = 0; m < 4; ++m)
          acc[m][n] = MFMA(buf[n], af[m], acc[m][n]);
    };
    cmp0(b0, 0); cmp0(b1, 1); cmp0(b2, 2); cmp0(b3, 3);
  }
  epi(be1);

  // ---- encoder layers 1,2 ----
#pragma unroll
  for (int m = 0; m < 4; ++m)
#pragma unroll
    for (int n = 0; n < 4; ++n) acc[m][n] = (f32x4){0.f, 0.f, 0.f, 0.f};
  phase16<512, 4>(wt + 65536 + (lane << 3), (wn << 2) << 4, sH, lrow, lhi, sw, acc);
  epi(be2);

#pragma unroll
  for (int m = 0; m < 4; ++m)
#pragma unroll
    for (int n = 0; n < 4; ++n) acc[m][n] = (f32x4){0.f, 0.f, 0.f, 0.f};
  phase16<512, 4>(wt + 327680 + (lane << 3), (wn << 2) << 4, sH, lrow, lhi, sw, acc);
  epi(be3);

  // ---- dump xseq (coalesced un-swizzle; read-only on sH) ----
#pragma unroll
  for (int p = 0; p < 8; ++p) {
    int id = (p << 9) + tid;
    int row = id >> 6, cc = id & 63;
    int slot = (cc & ~7) | ((cc & 7) ^ (row & 7));
    u16x8 v = *(const u16x8*)(sH + (row << 9) + (slot << 3));
    *(u16x8*)(xseq + ((size_t)(m0 + row) << 9) + (cc << 3)) = v;
  }

  // ---- recon decoder layer 1 (in place) ----
#pragma unroll
  for (int m = 0; m < 4; ++m)
#pragma unroll
    for (int n = 0; n < 4; ++n) acc[m][n] = (f32x4){0.f, 0.f, 0.f, 0.f};
  phase16<512, 4>(Wd1t + (lane << 3), (wn << 2) << 4, sH, lrow, lhi, sw, acc);
  epi(bd1);   // barrier inside orders dump reads + k-loop reads before writes

  // ---- recon decoder layer 2: N=128 ----
  f32x4 acc2[4];
#pragma unroll
  for (int m = 0; m < 4; ++m) acc2[m] = (f32x4){0.f, 0.f, 0.f, 0.f};
  phase16_n1(Wd2t + (lane << 3), wn << 4, sH, lrow, lhi, sw, acc2);
  {
    const int col0 = (wn << 4) + (lhi << 2);
    const float4v bv = *(const float4v*)(bd2 + col0);
#pragma unroll
    for (int m = 0; m < 4; ++m) {
      const int row = m * 16 + lrow;
      float4v o;
#pragma unroll
      for (int q = 0; q < 4; ++q) o[q] = fast_tanh(acc2[m][q] + bv[q]);
      *(float4v*)(outr + (size_t)(m0 + row) * IN_D + col0) = o;
    }
  }
}

// ---------------------------------------------------------------------------
// Fused 2-layer decoder (pred pass).
// ---------------------------------------------------------------------------
__global__ __launch_bounds__(512) void dec_fused_k(
    const unsigned short* __restrict__ X,
    const unsigned short* __restrict__ Wd1t,
    const unsigned short* __restrict__ Wd2t,
    const float* __restrict__ bd1, const float* __restrict__ bd2,
    float* __restrict__ out)
{
  __shared__ __attribute__((aligned(16))) unsigned short sH[64 * 512];  // 64 KB
  unsigned short* sX = sH;

  const int tid = threadIdx.x;
  const int m0 = blockIdx.x * 64;
  const int wave = tid >> 6, lane = tid & 63;
  const int wn = wave;
  const int lrow = lane & 15, lhi = lane >> 4, sw = lrow & 7;

  char* lX = (char*)sX + tid * 16;
#pragma unroll
  for (int p = 0; p < 8; ++p) {
    int id = (p << 9) + tid;
    int row = id >> 6, cc = id & 63;
    int gcc = (cc & ~7) | ((cc & 7) ^ (row & 7));
    gload_lds16(X + ((size_t)(m0 + row) << 9) + (gcc << 3), lX + (p << 13));
  }
  __syncthreads();

  f32x4 acc[4][4];
#pragma unroll
  for (int m = 0; m < 4; ++m)
#pragma unroll
    for (int n = 0; n < 4; ++n) acc[m][n] = (f32x4){0.f, 0.f, 0.f, 0.f};
  phase16<512, 4>(Wd1t + (lane << 3), (wn << 2) << 4, sX, lrow, lhi, sw, acc);

  __syncthreads();
#pragma unroll
  for (int n = 0; n < 4; ++n) {
    const int col0 = (wn << 6) + n * 16 + (lhi << 2);
    const float4v bv = *(const float4v*)(bd1 + col0);
    const int c2 = col0 >> 3;
#pragma unroll
    for (int m = 0; m < 4; ++m) {
      const int row = m * 16 + lrow;
      const int slot2 = (c2 & ~7) | ((c2 & 7) ^ (row & 7));
      u16x4 h;
#pragma unroll
      for (int q = 0; q < 4; ++q) h[q] = f2bf(fast_tanh(acc[m][n][q] + bv[q]));
      *(u16x4*)(sH + (row << 9) + (slot2 << 3) + (col0 & 7)) = h;
    }
  }
  __syncthreads();

  f32x4 acc2[4];
#pragma unroll
  for (int m = 0; m < 4; ++m) acc2[m] = (f32x4){0.f, 0.f, 0.f, 0.f};
  phase16_n1(Wd2t + (lane << 3), wn << 4, sH, lrow, lhi, sw, acc2);
  {
    const int col0 = (wn << 4) + (lhi << 2);
    const float4v bv = *(const float4v*)(bd2 + col0);
#pragma unroll
    for (int m = 0; m < 4; ++m) {
      const int row = m * 16 + lrow;
      float4v o;
#pragma unroll
      for (int q = 0; q < 4; ++q) o[q] = fast_tanh(acc2[m][q] + bv[q]);
      *(float4v*)(out + (size_t)(m0 + row) * IN_D + col0) = o;
    }
  }
}

// ---------------------------------------------------------------------------
// rec_all: ALL 5 recurrence steps in one kernel. Block = one chain (32 rows).
// ---------------------------------------------------------------------------
__global__ __launch_bounds__(512) void rec_all_k(
    const unsigned short* __restrict__ Wrec,
    unsigned short* __restrict__ xsall)   // in: xseq rows at t0; out: pred states
{
  __shared__ float xst[32][516];                                        // 64.5 KB
  __shared__ __attribute__((aligned(16))) unsigned short sA[32 * 512];  // 32 KB

  const int tid = threadIdx.x;
  const int chain = blockIdx.x;
  const int t0 = chain * 5;
  const int wave = tid >> 6, lane = tid & 63;
  const int wn = wave;
  const int lrow = lane & 15, lhi = lane >> 4, sw = lrow & 7;

  // coalesced init: xsall[row, t0, :] bf16 -> xst f32
#pragma unroll
  for (int p = 0; p < 4; ++p) {
    int id = (p << 9) + tid;
    int row = id >> 6, c8 = (id & 63) << 3;
    u16x8 v = *(const u16x8*)(xsall + (((size_t)row * T_SZ + t0) << 9) + c8);
#pragma unroll
    for (int e = 0; e < 8; ++e) xst[row][c8 + e] = bf2f(v[e]);
  }
  __syncthreads();

  const unsigned short* bl = Wrec + (lane << 3);
  const int nfb = (wn << 2) << 4;

  for (int s = 0; s < 5; ++s) {
    // stage tanh(xst) -> sA (swizzled)
#pragma unroll
    for (int p = 0; p < 4; ++p) {
      int id = (p << 9) + tid;
      int row = id >> 6, cc = id & 63;
      int gc = (cc & ~7) | ((cc & 7) ^ (row & 7));
      const float* src = &xst[row][gc << 3];
      float4v u0 = *(const float4v*)src;
      float4v u1 = *(const float4v*)(src + 4);
      u16x8 h;
      h[0] = f2bf(fast_tanh(u0[0])); h[1] = f2bf(fast_tanh(u0[1]));
      h[2] = f2bf(fast_tanh(u0[2])); h[3] = f2bf(fast_tanh(u0[3]));
      h[4] = f2bf(fast_tanh(u1[0])); h[5] = f2bf(fast_tanh(u1[1]));
      h[6] = f2bf(fast_tanh(u1[2])); h[7] = f2bf(fast_tanh(u1[3]));
      *(u16x8*)(sA + (row << 9) + (cc << 3)) = h;
    }
    __syncthreads();

    f32x4 acc[2][4];
#pragma unroll
    for (int m = 0; m < 2; ++m)
#pragma unroll
      for (int n = 0; n < 4; ++n) acc[m][n] = (f32x4){0.f, 0.f, 0.f, 0.f};

    phase16<512, 2>(bl, nfb, sA, lrow, lhi, sw, acc);
    __syncthreads();   // all staging/k-loop reads of xst & sA complete

    // epilogue: update xst in place + write pred state at t = t0 + s
    const int t = t0 + s;
#pragma unroll
    for (int n = 0; n < 4; ++n) {
      const int col0 = (wn << 6) + n * 16 + (lhi << 2);
#pragma unroll
      for (int m = 0; m < 2; ++m) {
        const int row = m * 16 + lrow;
        float4v x = *(const float4v*)(&xst[row][col0]);
        float4v xn;
#pragma unroll
        for (int q = 0; q < 4; ++q) xn[q] = x[q] + (acc[m][n][q] - x[q]) * INV_TAUX;
        *(float4v*)(&xst[row][col0]) = xn;
        if (t < T_SZ) {
          u16x4 h;
#pragma unroll
          for (int q = 0; q < 4; ++q) h[q] = f2bf(xn[q]);
          *(u16x4*)(xsall + ((size_t)row * T_SZ + t) * HID + col0) = h;
        }
      }
    }
    __syncthreads();   // xst updates visible before next step's staging
  }
}

// weight prep into fragment-linear layout:
// flat[((nf*nk+kk)*64+lane)*8+e] = B[nf*16+(lane&15)][kk*32+(lane>>4)*8+e]
__global__ void prep_k(const float* __restrict__ We1, const float* __restrict__ We2,
                       const float* __restrict__ We3, const float* __restrict__ Wd1,
                       const float* __restrict__ Wd2, const float* __restrict__ W,
                       unsigned short* __restrict__ wt) {
  int idx = blockIdx.x * blockDim.x + threadIdx.x;
  if (idx >= 1179648) return;
  unsigned short v;
  if (idx < 65536) {
    int i = idx, lane = (i >> 3) & 63, t2 = i >> 9;
    int kk = t2 & 3, nf = t2 >> 2;
    int n = (nf << 4) + (lane & 15), k = (kk << 5) + ((lane >> 4) << 3) + (i & 7);
    v = f2bf(We1[k * 512 + n]);
  } else if (idx < 327680) {
    int i = idx - 65536, lane = (i >> 3) & 63, t2 = i >> 9;
    int kk = t2 & 15, nf = t2 >> 4;
    int n = (nf << 4) + (lane & 15), k = (kk << 5) + ((lane >> 4) << 3) + (i & 7);
    v = f2bf(We2[k * 512 + n]);
  } else if (idx < 589824) {
    int i = idx - 327680, lane = (i >> 3) & 63, t2 = i >> 9;
    int kk = t2 & 15, nf = t2 >> 4;
    int n = (nf << 4) + (lane & 15), k = (kk << 5) + ((lane >> 4) << 3) + (i & 7);
    v = f2bf(We3[k * 512 + n]);
  } else if (idx < 851968) {
    int i = idx - 589824, lane = (i >> 3) & 63, t2 = i >> 9;
    int kk = t2 & 15, nf = t2 >> 4;
    int n = (nf << 4) + (lane & 15), k = (kk << 5) + ((lane >> 4) << 3) + (i & 7);
    v = f2bf(Wd1[k * 512 + n]);
  } else if (idx < 917504) {
    int i = idx - 851968, lane = (i >> 3) & 63, t2 = i >> 9;
    int kk = t2 & 15, nf = t2 >> 4;
    int n = (nf << 4) + (lane & 15), k = (kk << 5) + ((lane >> 4) << 3) + (i & 7);
    v = f2bf(Wd2[k * 128 + n]);
  } else {
    int i = idx - 917504, lane = (i >> 3) & 63, t2 = i >> 9;
    int kk = t2 & 15, nf = t2 >> 4;
    int n = (nf << 4) + (lane & 15), k = (kk << 5) + ((lane >> 4) << 3) + (i & 7);
    v = f2bf(W[(n << 9) + k]);
  }
  wt[idx] = v;
}

__global__ void sentinel_k(float* out, float v) { out[0] = v; }

extern "C" void kernel_launch(void* const* d_in, const int* in_sizes, int n_in,
                              void* d_out, int out_size, void* d_ws, size_t ws_size,
                              hipStream_t stream) {
  const float* in_seq = (const float*)d_in[0];
  const float* We1 = (const float*)d_in[1];
  const float* be1 = (const float*)d_in[2];
  const float* We2 = (const float*)d_in[3];
  const float* be2 = (const float*)d_in[4];
  const float* We3 = (const float*)d_in[5];
  const float* be3 = (const float*)d_in[6];
  const float* Wd1 = (const float*)d_in[7];
  const float* bd1 = (const float*)d_in[8];
  const float* Wd2 = (const float*)d_in[9];
  const float* bd2 = (const float*)d_in[10];
  const float* W   = (const float*)d_in[11];

  const int NROW = B_SZ * T_SZ;                       // 65536
  const size_t OFF_XSEQ = 0;                          // 67,108,864 B
  const size_t OFF_WT   = (size_t)NROW * HID * 2;     // 67,108,864
  const size_t REQUIRED = OFF_WT + 2359296;           // 69,468,160

  float* outp = (float*)d_out;
  float* outr = outp + (size_t)NROW * IN_D;

  if (ws_size < REQUIRED) {
    sentinel_k<<<1, 1, 0, stream>>>(outp, (float)(ws_size >> 20));
    return;
  }

  char* ws = (char*)d_ws;
  unsigned short* xseq = (unsigned short*)(ws + OFF_XSEQ);  // reused as xsall
  unsigned short* wt   = (unsigned short*)(ws + OFF_WT);
  unsigned short* Wd1t = wt + 589824;
  unsigned short* Wd2t = wt + 851968;
  unsigned short* Wrec = wt + 917504;

  prep_k<<<4608, 256, 0, stream>>>(We1, We2, We3, Wd1, Wd2, W, wt);
  enc5_k<<<1024, 512, 0, stream>>>(in_seq, wt, be1, be2, be3,
                                   Wd1t, Wd2t, bd1, bd2, xseq, outr);
  rec_all_k<<<NCHAIN, 512, 0, stream>>>(Wrec, xseq);
  dec_fused_k<<<1024, 512, 0, stream>>>(xseq, Wd1t, Wd2t, bd1, bd2, outp);
}

// Round 15
// 416.698 us; speedup vs baseline: 1.1570x; 1.1570x over previous
//
#include <hip/hip_runtime.h>
#include <stdint.h>

#define B_SZ  32
#define T_SZ  2048
#define IN_D  128
#define HID   512
#define NCHAIN 410              // ceil(T/5)
#define INV_TAUX 0.005f         // 1/200

typedef __attribute__((ext_vector_type(8))) short bf16x8;
typedef __attribute__((ext_vector_type(4))) float f32x4;
typedef __attribute__((ext_vector_type(4))) float float4v;
typedef __attribute__((ext_vector_type(4))) unsigned short u16x4;
typedef __attribute__((ext_vector_type(8))) unsigned short u16x8;

// Operands SWAPPED: mfma(b, a) => D^T. Lane holds row = frag_m*16 + (lane&15),
// cols = frag_n*16 + (lane>>4)*4 + q (4 consecutive) -> vectorized epilogues.
#define MFMA(b, a, c) __builtin_amdgcn_mfma_f32_16x16x32_bf16((b), (a), (c), 0, 0, 0)

__device__ __forceinline__ unsigned short f2bf(float x) {
  union { float f; unsigned int u; } v; v.f = x;
  unsigned int r = v.u + 0x7FFFu + ((v.u >> 16) & 1u);  // RNE
  return (unsigned short)(r >> 16);
}
__device__ __forceinline__ float bf2f(unsigned short b) {
  union { unsigned int u; float f; } v; v.u = ((unsigned int)b) << 16;
  return v.f;
}
__device__ __forceinline__ float fast_tanh(float x) {
  float ax = fabsf(x);
  float e = __expf(-2.0f * ax);
  float r = (1.0f - e) * __builtin_amdgcn_rcpf(1.0f + e);
  return x < 0.0f ? -r : r;
}
__device__ __forceinline__ void gload_lds16(const void* g, void* l) {
  __builtin_amdgcn_global_load_lds(
      reinterpret_cast<__attribute__((address_space(1))) void*>(reinterpret_cast<uintptr_t>(g)),
      reinterpret_cast<__attribute__((address_space(3))) void*>(reinterpret_cast<uintptr_t>(l)),
      16, 0, 0);
}

// ---------------------------------------------------------------------------
// Weights FRAGMENT-LINEAR (see prep_k). 1m x 8n wave layout: wave wn owns all
// block rows x cols [wn*64, wn*64+64). ROUND-15: 128 rows/block (MF=8) --
// doubles MFMA per B-load (latency cover) and halves chip-wide weight
// re-fetch. Depth-2 B-prefetch (compiler-scheduled; the round-14 4-deep
// manual ladder regressed -- m131-m141 lesson confirmed).
// ---------------------------------------------------------------------------

// ---------------------------------------------------------------------------
// enc5: 3 encoder layers + xseq dump + 2 recon-decoder layers, one kernel.
// 512 thr = 8 waves, 128 rows/block, LDS 128 KB.
// ---------------------------------------------------------------------------
__global__ __launch_bounds__(512) void enc5_k(
    const float* __restrict__ in_seq,
    const unsigned short* __restrict__ wt,
    const float* __restrict__ be1, const float* __restrict__ be2,
    const float* __restrict__ be3,
    const unsigned short* __restrict__ Wd1t,
    const unsigned short* __restrict__ Wd2t,
    const float* __restrict__ bd1, const float* __restrict__ bd2,
    unsigned short* __restrict__ xseq,
    float* __restrict__ outr)
{
  __shared__ __attribute__((aligned(16))) unsigned short sH[128 * 512];  // 128 KB
  unsigned short* sA = sH;   // alias: input tile (128x128) in sH's head

  const int tid = threadIdx.x;
  const int m0 = blockIdx.x * 128;
  const int wave = tid >> 6, lane = tid & 63;
  const int wn = wave;
  const int lrow = lane & 15, lhi = lane >> 4, sw = lrow & 7;

  // stage input tile f32 -> bf16, chunk-swizzled (128 rows x 16 chunks)
#pragma unroll
  for (int p = 0; p < 4; ++p) {
    int id = (p << 9) + tid;
    int row = id >> 4, cc = id & 15;
    const float* src = in_seq + (size_t)(m0 + row) * IN_D + (cc << 3);
    float4v u0 = *(const float4v*)src;
    float4v u1 = *(const float4v*)(src + 4);
    u16x8 h;
    h[0] = f2bf(u0[0]); h[1] = f2bf(u0[1]); h[2] = f2bf(u0[2]); h[3] = f2bf(u0[3]);
    h[4] = f2bf(u1[0]); h[5] = f2bf(u1[1]); h[6] = f2bf(u1[2]); h[7] = f2bf(u1[3]);
    int slot = (cc & 8) | ((cc & 7) ^ (row & 7));
    *(u16x8*)(sA + (row << 7) + (slot << 3)) = h;
  }
  __syncthreads();

  f32x4 acc[8][4];
  const unsigned short* Bts[3] = {wt, wt + 65536, wt + 327680};
  const float* bss[3] = {be1, be2, be3};

  // ---- 3 encoder layers (in-place in sH) ----
  for (int l = 0; l < 3; ++l) {
    const int lstr = (l == 0) ? 128 : 512;
    const int nk = (l == 0) ? 4 : 16;
    const unsigned short* bl = Bts[l] + (lane << 3);
    const int nfb = (wn << 2) * nk;
    const float* bias = bss[l];

#pragma unroll
    for (int m = 0; m < 8; ++m)
#pragma unroll
      for (int n = 0; n < 4; ++n) acc[m][n] = (f32x4){0.f, 0.f, 0.f, 0.f};

    bf16x8 b0[4], b1[4];
#pragma unroll
    for (int n = 0; n < 4; ++n)
      b0[n] = *(const bf16x8*)(bl + ((nfb + n * nk) << 9));

    for (int kk = 0; kk < nk; kk += 2) {
#pragma unroll
      for (int n = 0; n < 4; ++n)
        b1[n] = *(const bf16x8*)(bl + ((nfb + n * nk + kk + 1) << 9));
      {
        const int c = (kk << 2) + lhi;
        const int slot = (c & ~7) | ((c & 7) ^ sw);
        bf16x8 af[8];
#pragma unroll
        for (int m = 0; m < 8; ++m)
          af[m] = *(const bf16x8*)(sH + (m * 16 + lrow) * lstr + (slot << 3));
#pragma unroll
        for (int n = 0; n < 4; ++n)
#pragma unroll
          for (int m = 0; m < 8; ++m)
            acc[m][n] = MFMA(b0[n], af[m], acc[m][n]);
      }
      if (kk + 2 < nk) {
#pragma unroll
        for (int n = 0; n < 4; ++n)
          b0[n] = *(const bf16x8*)(bl + ((nfb + n * nk + kk + 2) << 9));
      }
      {
        const int c = ((kk + 1) << 2) + lhi;
        const int slot = (c & ~7) | ((c & 7) ^ sw);
        bf16x8 af[8];
#pragma unroll
        for (int m = 0; m < 8; ++m)
          af[m] = *(const bf16x8*)(sH + (m * 16 + lrow) * lstr + (slot << 3));
#pragma unroll
        for (int n = 0; n < 4; ++n)
#pragma unroll
          for (int m = 0; m < 8; ++m)
            acc[m][n] = MFMA(b1[n], af[m], acc[m][n]);
      }
    }
    __syncthreads();
    // epilogue: acc[m][n][q] = D[row=m*16+lrow][col=wn*64+n*16+lhi*4+q]
#pragma unroll
    for (int n = 0; n < 4; ++n) {
      const int col0 = (wn << 6) + n * 16 + (lhi << 2);
      const float4v bv = *(const float4v*)(bias + col0);
      const int c2 = col0 >> 3;
#pragma unroll
      for (int m = 0; m < 8; ++m) {
        const int row = m * 16 + lrow;
        const int slot2 = (c2 & ~7) | ((c2 & 7) ^ (row & 7));
        u16x4 h;
#pragma unroll
        for (int q = 0; q < 4; ++q) h[q] = f2bf(fast_tanh(acc[m][n][q] + bv[q]));
        *(u16x4*)(sH + (row << 9) + (slot2 << 3) + (col0 & 7)) = h;
      }
    }
    __syncthreads();
  }

  // ---- dump xseq (coalesced un-swizzle; read-only on sH) ----
#pragma unroll
  for (int p = 0; p < 16; ++p) {
    int id = (p << 9) + tid;
    int row = id >> 6, cc = id & 63;
    int slot = (cc & ~7) | ((cc & 7) ^ (row & 7));
    u16x8 v = *(const u16x8*)(sH + (row << 9) + (slot << 3));
    *(u16x8*)(xseq + ((size_t)(m0 + row) << 9) + (cc << 3)) = v;
  }

  // ---- recon decoder layer 1 (reads sH-as-X, writes sH-as-d1 in place) ----
#pragma unroll
  for (int m = 0; m < 8; ++m)
#pragma unroll
    for (int n = 0; n < 4; ++n) acc[m][n] = (f32x4){0.f, 0.f, 0.f, 0.f};

  {
    const unsigned short* bl = Wd1t + (lane << 3);
    const int nfb = (wn << 2) << 4;
    bf16x8 b0[4], b1[4];
#pragma unroll
    for (int n = 0; n < 4; ++n)
      b0[n] = *(const bf16x8*)(bl + ((nfb + (n << 4)) << 9));
    for (int kk = 0; kk < 16; kk += 2) {
#pragma unroll
      for (int n = 0; n < 4; ++n)
        b1[n] = *(const bf16x8*)(bl + ((nfb + (n << 4) + kk + 1) << 9));
      {
        const int c = (kk << 2) + lhi;
        const int slot = (c & ~7) | ((c & 7) ^ sw);
        bf16x8 af[8];
#pragma unroll
        for (int m = 0; m < 8; ++m)
          af[m] = *(const bf16x8*)(sH + ((m * 16 + lrow) << 9) + (slot << 3));
#pragma unroll
        for (int n = 0; n < 4; ++n)
#pragma unroll
          for (int m = 0; m < 8; ++m)
            acc[m][n] = MFMA(b0[n], af[m], acc[m][n]);
      }
      if (kk + 2 < 16) {
#pragma unroll
        for (int n = 0; n < 4; ++n)
          b0[n] = *(const bf16x8*)(bl + ((nfb + (n << 4) + kk + 2) << 9));
      }
      {
        const int c = ((kk + 1) << 2) + lhi;
        const int slot = (c & ~7) | ((c & 7) ^ sw);
        bf16x8 af[8];
#pragma unroll
        for (int m = 0; m < 8; ++m)
          af[m] = *(const bf16x8*)(sH + ((m * 16 + lrow) << 9) + (slot << 3));
#pragma unroll
        for (int n = 0; n < 4; ++n)
#pragma unroll
          for (int m = 0; m < 8; ++m)
            acc[m][n] = MFMA(b1[n], af[m], acc[m][n]);
      }
    }
  }
  __syncthreads();   // all sH(X) reads + dump reads done -> overwrite as d1
#pragma unroll
  for (int n = 0; n < 4; ++n) {
    const int col0 = (wn << 6) + n * 16 + (lhi << 2);
    const float4v bv = *(const float4v*)(bd1 + col0);
    const int c2 = col0 >> 3;
#pragma unroll
    for (int m = 0; m < 8; ++m) {
      const int row = m * 16 + lrow;
      const int slot2 = (c2 & ~7) | ((c2 & 7) ^ (row & 7));
      u16x4 h;
#pragma unroll
      for (int q = 0; q < 4; ++q) h[q] = f2bf(fast_tanh(acc[m][n][q] + bv[q]));
      *(u16x4*)(sH + (row << 9) + (slot2 << 3) + (col0 & 7)) = h;
    }
  }
  __syncthreads();

  // ---- recon decoder layer 2: N=128, wave owns one 16-col frag ----
  f32x4 acc2[8];
#pragma unroll
  for (int m = 0; m < 8; ++m) acc2[m] = (f32x4){0.f, 0.f, 0.f, 0.f};

  {
    const unsigned short* bl = Wd2t + (lane << 3);
    const int nfb = wn << 4;
    bf16x8 c0, c1;
    c0 = *(const bf16x8*)(bl + ((nfb + 0) << 9));
    for (int kk = 0; kk < 16; kk += 2) {
      c1 = *(const bf16x8*)(bl + ((nfb + kk + 1) << 9));
      {
        const int c = (kk << 2) + lhi;
        const int slot = (c & ~7) | ((c & 7) ^ sw);
#pragma unroll
        for (int m = 0; m < 8; ++m) {
          bf16x8 af = *(const bf16x8*)(sH + ((m * 16 + lrow) << 9) + (slot << 3));
          acc2[m] = MFMA(c0, af, acc2[m]);
        }
      }
      if (kk + 2 < 16)
        c0 = *(const bf16x8*)(bl + ((nfb + kk + 2) << 9));
      {
        const int c = ((kk + 1) << 2) + lhi;
        const int slot = (c & ~7) | ((c & 7) ^ sw);
#pragma unroll
        for (int m = 0; m < 8; ++m) {
          bf16x8 af = *(const bf16x8*)(sH + ((m * 16 + lrow) << 9) + (slot << 3));
          acc2[m] = MFMA(c1, af, acc2[m]);
        }
      }
    }
  }
  {
    const int col0 = (wn << 4) + (lhi << 2);
    const float4v bv = *(const float4v*)(bd2 + col0);
#pragma unroll
    for (int m = 0; m < 8; ++m) {
      const int row = m * 16 + lrow;
      float4v o;
#pragma unroll
      for (int q = 0; q < 4; ++q) o[q] = fast_tanh(acc2[m][q] + bv[q]);
      *(float4v*)(outr + (size_t)(m0 + row) * IN_D + col0) = o;
    }
  }
}

// ---------------------------------------------------------------------------
// Fused 2-layer decoder (pred pass). 128 rows/block, LDS 128 KB.
// ---------------------------------------------------------------------------
__global__ __launch_bounds__(512) void dec_fused_k(
    const unsigned short* __restrict__ X,
    const unsigned short* __restrict__ Wd1t,
    const unsigned short* __restrict__ Wd2t,
    const float* __restrict__ bd1, const float* __restrict__ bd2,
    float* __restrict__ out)
{
  __shared__ __attribute__((aligned(16))) unsigned short sH[128 * 512];  // 128 KB
  unsigned short* sX = sH;

  const int tid = threadIdx.x;
  const int m0 = blockIdx.x * 128;
  const int wave = tid >> 6, lane = tid & 63;
  const int wn = wave;
  const int lrow = lane & 15, lhi = lane >> 4, sw = lrow & 7;

  char* lX = (char*)sX + tid * 16;
#pragma unroll
  for (int p = 0; p < 16; ++p) {
    int id = (p << 9) + tid;
    int row = id >> 6, cc = id & 63;
    int gcc = (cc & ~7) | ((cc & 7) ^ (row & 7));
    gload_lds16(X + ((size_t)(m0 + row) << 9) + (gcc << 3), lX + (p << 13));
  }
  __syncthreads();

  f32x4 acc[8][4];
#pragma unroll
  for (int m = 0; m < 8; ++m)
#pragma unroll
    for (int n = 0; n < 4; ++n) acc[m][n] = (f32x4){0.f, 0.f, 0.f, 0.f};

  {
    const unsigned short* bl = Wd1t + (lane << 3);
    const int nfb = (wn << 2) << 4;
    bf16x8 b0[4], b1[4];
#pragma unroll
    for (int n = 0; n < 4; ++n)
      b0[n] = *(const bf16x8*)(bl + ((nfb + (n << 4)) << 9));
    for (int kk = 0; kk < 16; kk += 2) {
#pragma unroll
      for (int n = 0; n < 4; ++n)
        b1[n] = *(const bf16x8*)(bl + ((nfb + (n << 4) + kk + 1) << 9));
      {
        const int c = (kk << 2) + lhi;
        const int slot = (c & ~7) | ((c & 7) ^ sw);
        bf16x8 af[8];
#pragma unroll
        for (int m = 0; m < 8; ++m)
          af[m] = *(const bf16x8*)(sX + ((m * 16 + lrow) << 9) + (slot << 3));
#pragma unroll
        for (int n = 0; n < 4; ++n)
#pragma unroll
          for (int m = 0; m < 8; ++m)
            acc[m][n] = MFMA(b0[n], af[m], acc[m][n]);
      }
      if (kk + 2 < 16) {
#pragma unroll
        for (int n = 0; n < 4; ++n)
          b0[n] = *(const bf16x8*)(bl + ((nfb + (n << 4) + kk + 2) << 9));
      }
      {
        const int c = ((kk + 1) << 2) + lhi;
        const int slot = (c & ~7) | ((c & 7) ^ sw);
        bf16x8 af[8];
#pragma unroll
        for (int m = 0; m < 8; ++m)
          af[m] = *(const bf16x8*)(sX + ((m * 16 + lrow) << 9) + (slot << 3));
#pragma unroll
        for (int n = 0; n < 4; ++n)
#pragma unroll
          for (int m = 0; m < 8; ++m)
            acc[m][n] = MFMA(b1[n], af[m], acc[m][n]);
      }
    }
  }
  __syncthreads();
#pragma unroll
  for (int n = 0; n < 4; ++n) {
    const int col0 = (wn << 6) + n * 16 + (lhi << 2);
    const float4v bv = *(const float4v*)(bd1 + col0);
    const int c2 = col0 >> 3;
#pragma unroll
    for (int m = 0; m < 8; ++m) {
      const int row = m * 16 + lrow;
      const int slot2 = (c2 & ~7) | ((c2 & 7) ^ (row & 7));
      u16x4 h;
#pragma unroll
      for (int q = 0; q < 4; ++q) h[q] = f2bf(fast_tanh(acc[m][n][q] + bv[q]));
      *(u16x4*)(sH + (row << 9) + (slot2 << 3) + (col0 & 7)) = h;
    }
  }
  __syncthreads();

  f32x4 acc2[8];
#pragma unroll
  for (int m = 0; m < 8; ++m) acc2[m] = (f32x4){0.f, 0.f, 0.f, 0.f};

  {
    const unsigned short* bl = Wd2t + (lane << 3);
    const int nfb = wn << 4;
    bf16x8 c0, c1;
    c0 = *(const bf16x8*)(bl + ((nfb + 0) << 9));
    for (int kk = 0; kk < 16; kk += 2) {
      c1 = *(const bf16x8*)(bl + ((nfb + kk + 1) << 9));
      {
        const int c = (kk << 2) + lhi;
        const int slot = (c & ~7) | ((c & 7) ^ sw);
#pragma unroll
        for (int m = 0; m < 8; ++m) {
          bf16x8 af = *(const bf16x8*)(sH + ((m * 16 + lrow) << 9) + (slot << 3));
          acc2[m] = MFMA(c0, af, acc2[m]);
        }
      }
      if (kk + 2 < 16)
        c0 = *(const bf16x8*)(bl + ((nfb + kk + 2) << 9));
      {
        const int c = ((kk + 1) << 2) + lhi;
        const int slot = (c & ~7) | ((c & 7) ^ sw);
#pragma unroll
        for (int m = 0; m < 8; ++m) {
          bf16x8 af = *(const bf16x8*)(sH + ((m * 16 + lrow) << 9) + (slot << 3));
          acc2[m] = MFMA(c1, af, acc2[m]);
        }
      }
    }
  }
  {
    const int col0 = (wn << 4) + (lhi << 2);
    const float4v bv = *(const float4v*)(bd2 + col0);
#pragma unroll
    for (int m = 0; m < 8; ++m) {
      const int row = m * 16 + lrow;
      float4v o;
#pragma unroll
      for (int q = 0; q < 4; ++q) o[q] = fast_tanh(acc2[m][q] + bv[q]);
      *(float4v*)(out + (size_t)(m0 + row) * IN_D + col0) = o;
    }
  }
}

// ---------------------------------------------------------------------------
// rec_all: ALL 5 recurrence steps in one kernel. Block = one chain (32 rows).
// (round-13 proven version, depth-2 prefetch)
// ---------------------------------------------------------------------------
__global__ __launch_bounds__(512) void rec_all_k(
    const unsigned short* __restrict__ Wrec,
    unsigned short* __restrict__ xsall)   // in: xseq rows at t0; out: pred states
{
  __shared__ float xst[32][516];                                        // 64.5 KB
  __shared__ __attribute__((aligned(16))) unsigned short sA[32 * 512];  // 32 KB

  const int tid = threadIdx.x;
  const int chain = blockIdx.x;
  const int t0 = chain * 5;
  const int wave = tid >> 6, lane = tid & 63;
  const int wn = wave;
  const int lrow = lane & 15, lhi = lane >> 4, sw = lrow & 7;

  // coalesced init: xsall[row, t0, :] bf16 -> xst f32
#pragma unroll
  for (int p = 0; p < 4; ++p) {
    int id = (p << 9) + tid;
    int row = id >> 6, c8 = (id & 63) << 3;
    u16x8 v = *(const u16x8*)(xsall + (((size_t)row * T_SZ + t0) << 9) + c8);
#pragma unroll
    for (int e = 0; e < 8; ++e) xst[row][c8 + e] = bf2f(v[e]);
  }
  __syncthreads();

  const unsigned short* bl = Wrec + (lane << 3);
  const int nfb = (wn << 2) << 4;

  for (int s = 0; s < 5; ++s) {
    // stage tanh(xst) -> sA (swizzled)
#pragma unroll
    for (int p = 0; p < 4; ++p) {
      int id = (p << 9) + tid;
      int row = id >> 6, cc = id & 63;
      int gc = (cc & ~7) | ((cc & 7) ^ (row & 7));
      const float* src = &xst[row][gc << 3];
      float4v u0 = *(const float4v*)src;
      float4v u1 = *(const float4v*)(src + 4);
      u16x8 h;
      h[0] = f2bf(fast_tanh(u0[0])); h[1] = f2bf(fast_tanh(u0[1]));
      h[2] = f2bf(fast_tanh(u0[2])); h[3] = f2bf(fast_tanh(u0[3]));
      h[4] = f2bf(fast_tanh(u1[0])); h[5] = f2bf(fast_tanh(u1[1]));
      h[6] = f2bf(fast_tanh(u1[2])); h[7] = f2bf(fast_tanh(u1[3]));
      *(u16x8*)(sA + (row << 9) + (cc << 3)) = h;
    }
    __syncthreads();

    f32x4 acc[2][4];
#pragma unroll
    for (int m = 0; m < 2; ++m)
#pragma unroll
      for (int n = 0; n < 4; ++n) acc[m][n] = (f32x4){0.f, 0.f, 0.f, 0.f};

    bf16x8 b0[4], b1[4];
#pragma unroll
    for (int n = 0; n < 4; ++n)
      b0[n] = *(const bf16x8*)(bl + ((nfb + (n << 4)) << 9));
    for (int kk = 0; kk < 16; kk += 2) {
#pragma unroll
      for (int n = 0; n < 4; ++n)
        b1[n] = *(const bf16x8*)(bl + ((nfb + (n << 4) + kk + 1) << 9));
      {
        const int c = (kk << 2) + lhi;
        const int slot = (c & ~7) | ((c & 7) ^ sw);
        bf16x8 af0 = *(const bf16x8*)(sA + (lrow << 9) + (slot << 3));
        bf16x8 af1 = *(const bf16x8*)(sA + ((16 + lrow) << 9) + (slot << 3));
#pragma unroll
        for (int n = 0; n < 4; ++n) {
          acc[0][n] = MFMA(b0[n], af0, acc[0][n]);
          acc[1][n] = MFMA(b0[n], af1, acc[1][n]);
        }
      }
      if (kk + 2 < 16) {
#pragma unroll
        for (int n = 0; n < 4; ++n)
          b0[n] = *(const bf16x8*)(bl + ((nfb + (n << 4) + kk + 2) << 9));
      }
      {
        const int c = ((kk + 1) << 2) + lhi;
        const int slot = (c & ~7) | ((c & 7) ^ sw);
        bf16x8 af0 = *(const bf16x8*)(sA + (lrow << 9) + (slot << 3));
        bf16x8 af1 = *(const bf16x8*)(sA + ((16 + lrow) << 9) + (slot << 3));
#pragma unroll
        for (int n = 0; n < 4; ++n) {
          acc[0][n] = MFMA(b1[n], af0, acc[0][n]);
          acc[1][n] = MFMA(b1[n], af1, acc[1][n]);
        }
      }
    }
    __syncthreads();   // all staging/k-loop reads of xst & sA complete

    // epilogue: update xst in place + write pred state at t = t0 + s
    const int t = t0 + s;
#pragma unroll
    for (int n = 0; n < 4; ++n) {
      const int col0 = (wn << 6) + n * 16 + (lhi << 2);
#pragma unroll
      for (int m = 0; m < 2; ++m) {
        const int row = m * 16 + lrow;
        float4v x = *(const float4v*)(&xst[row][col0]);
        float4v xn;
#pragma unroll
        for (int q = 0; q < 4; ++q) xn[q] = x[q] + (acc[m][n][q] - x[q]) * INV_TAUX;
        *(float4v*)(&xst[row][col0]) = xn;
        if (t < T_SZ) {
          u16x4 h;
#pragma unroll
          for (int q = 0; q < 4; ++q) h[q] = f2bf(xn[q]);
          *(u16x4*)(xsall + ((size_t)row * T_SZ + t) * HID + col0) = h;
        }
      }
    }
    __syncthreads();   // xst updates visible before next step's staging
  }
}

// weight prep into fragment-linear layout:
// flat[((nf*nk+kk)*64+lane)*8+e] = B[nf*16+(lane&15)][kk*32+(lane>>4)*8+e]
__global__ void prep_k(const float* __restrict__ We1, const float* __restrict__ We2,
                       const float* __restrict__ We3, const float* __restrict__ Wd1,
                       const float* __restrict__ Wd2, const float* __restrict__ W,
                       unsigned short* __restrict__ wt) {
  int idx = blockIdx.x * blockDim.x + threadIdx.x;
  if (idx >= 1179648) return;
  unsigned short v;
  if (idx < 65536) {
    int i = idx, lane = (i >> 3) & 63, t2 = i >> 9;
    int kk = t2 & 3, nf = t2 >> 2;
    int n = (nf << 4) + (lane & 15), k = (kk << 5) + ((lane >> 4) << 3) + (i & 7);
    v = f2bf(We1[k * 512 + n]);
  } else if (idx < 327680) {
    int i = idx - 65536, lane = (i >> 3) & 63, t2 = i >> 9;
    int kk = t2 & 15, nf = t2 >> 4;
    int n = (nf << 4) + (lane & 15), k = (kk << 5) + ((lane >> 4) << 3) + (i & 7);
    v = f2bf(We2[k * 512 + n]);
  } else if (idx < 589824) {
    int i = idx - 327680, lane = (i >> 3) & 63, t2 = i >> 9;
    int kk = t2 & 15, nf = t2 >> 4;
    int n = (nf << 4) + (lane & 15), k = (kk << 5) + ((lane >> 4) << 3) + (i & 7);
    v = f2bf(We3[k * 512 + n]);
  } else if (idx < 851968) {
    int i = idx - 589824, lane = (i >> 3) & 63, t2 = i >> 9;
    int kk = t2 & 15, nf = t2 >> 4;
    int n = (nf << 4) + (lane & 15), k = (kk << 5) + ((lane >> 4) << 3) + (i & 7);
    v = f2bf(Wd1[k * 512 + n]);
  } else if (idx < 917504) {
    int i = idx - 851968, lane = (i >> 3) & 63, t2 = i >> 9;
    int kk = t2 & 15, nf = t2 >> 4;
    int n = (nf << 4) + (lane & 15), k = (kk << 5) + ((lane >> 4) << 3) + (i & 7);
    v = f2bf(Wd2[k * 128 + n]);
  } else {
    int i = idx - 917504, lane = (i >> 3) & 63, t2 = i >> 9;
    int kk = t2 & 15, nf = t2 >> 4;
    int n = (nf << 4) + (lane & 15), k = (kk << 5) + ((lane >> 4) << 3) + (i & 7);
    v = f2bf(W[(n << 9) + k]);
  }
  wt[idx] = v;
}

__global__ void sentinel_k(float* out, float v) { out[0] = v; }

extern "C" void kernel_launch(void* const* d_in, const int* in_sizes, int n_in,
                              void* d_out, int out_size, void* d_ws, size_t ws_size,
                              hipStream_t stream) {
  const float* in_seq = (const float*)d_in[0];
  const float* We1 = (const float*)d_in[1];
  const float* be1 = (const float*)d_in[2];
  const float* We2 = (const float*)d_in[3];
  const float* be2 = (const float*)d_in[4];
  const float* We3 = (const float*)d_in[5];
  const float* be3 = (const float*)d_in[6];
  const float* Wd1 = (const float*)d_in[7];
  const float* bd1 = (const float*)d_in[8];
  const float* Wd2 = (const float*)d_in[9];
  const float* bd2 = (const float*)d_in[10];
  const float* W   = (const float*)d_in[11];

  const int NROW = B_SZ * T_SZ;                       // 65536
  const size_t OFF_XSEQ = 0;                          // 67,108,864 B
  const size_t OFF_WT   = (size_t)NROW * HID * 2;     // 67,108,864
  const size_t REQUIRED = OFF_WT + 2359296;           // 69,468,160

  float* outp = (float*)d_out;
  float* outr = outp + (size_t)NROW * IN_D;

  if (ws_size < REQUIRED) {
    sentinel_k<<<1, 1, 0, stream>>>(outp, (float)(ws_size >> 20));
    return;
  }

  char* ws = (char*)d_ws;
  unsigned short* xseq = (unsigned short*)(ws + OFF_XSEQ);  // reused as xsall
  unsigned short* wt   = (unsigned short*)(ws + OFF_WT);
  unsigned short* Wd1t = wt + 589824;
  unsigned short* Wd2t = wt + 851968;
  unsigned short* Wrec = wt + 917504;

  prep_k<<<4608, 256, 0, stream>>>(We1, We2, We3, Wd1, Wd2, W, wt);
  enc5_k<<<512, 512, 0, stream>>>(in_seq, wt, be1, be2, be3,
                                  Wd1t, Wd2t, bd1, bd2, xseq, outr);
  rec_all_k<<<NCHAIN, 512, 0, stream>>>(Wrec, xseq);
  dec_fused_k<<<512, 512, 0, stream>>>(xseq, Wd1t, Wd2t, bd1, bd2, outp);
}

// Round 16
// 415.812 us; speedup vs baseline: 1.1595x; 1.0021x over previous
//
#include <hip/hip_runtime.h>
#include <stdint.h>

#define B_SZ  32
#define T_SZ  2048
#define IN_D  128
#define HID   512
#define NCHAIN 410              // ceil(T/5)
#define INV_TAUX 0.005f         // 1/200

typedef __attribute__((ext_vector_type(8))) short bf16x8;
typedef __attribute__((ext_vector_type(4))) float f32x4;
typedef __attribute__((ext_vector_type(4))) float float4v;
typedef __attribute__((ext_vector_type(4))) unsigned short u16x4;
typedef __attribute__((ext_vector_type(8))) unsigned short u16x8;

// Operands SWAPPED: mfma(b, a) => D^T. Lane holds row = frag_m*16 + (lane&15),
// cols = frag_n*16 + (lane>>4)*4 + q (4 consecutive) -> vectorized epilogues.
#define MFMA(b, a, c) __builtin_amdgcn_mfma_f32_16x16x32_bf16((b), (a), (c), 0, 0, 0)

__device__ __forceinline__ unsigned short f2bf(float x) {
  union { float f; unsigned int u; } v; v.f = x;
  unsigned int r = v.u + 0x7FFFu + ((v.u >> 16) & 1u);  // RNE
  return (unsigned short)(r >> 16);
}
__device__ __forceinline__ float bf2f(unsigned short b) {
  union { unsigned int u; float f; } v; v.u = ((unsigned int)b) << 16;
  return v.f;
}
__device__ __forceinline__ float fast_tanh(float x) {
  float ax = fabsf(x);
  float e = __expf(-2.0f * ax);
  float r = (1.0f - e) * __builtin_amdgcn_rcpf(1.0f + e);
  return x < 0.0f ? -r : r;
}
__device__ __forceinline__ void gload_lds16(const void* g, void* l) {
  __builtin_amdgcn_global_load_lds(
      reinterpret_cast<__attribute__((address_space(1))) void*>(reinterpret_cast<uintptr_t>(g)),
      reinterpret_cast<__attribute__((address_space(3))) void*>(reinterpret_cast<uintptr_t>(l)),
      16, 0, 0);
}

// ---------------------------------------------------------------------------
// Weights FRAGMENT-LINEAR (see prep_k).
// ROUND-16: 1024-thread blocks (16 waves = 4 waves/SIMD GUARANTEED) for
// enc5/dec -- every prior config ran 2 waves/SIMD (latency-starved K-loops;
// occupancy never exceeded 1x8-wave block across 5 attempts). Wave = (wm
// row-half, wn col-slice); per-wave body = round-13's proven MF=4 (84 VGPR).
// B-frags duplicated across row-half pairs (same addr -> L1/L2 hit).
// ---------------------------------------------------------------------------

// ---------------------------------------------------------------------------
// enc5: 3 encoder layers + xseq dump + 2 recon-decoder layers, one kernel.
// 1024 thr = 16 waves (2 wm x 8 wn), 128 rows/block, LDS 128 KB.
// ---------------------------------------------------------------------------
__global__ __launch_bounds__(1024) void enc5_k(
    const float* __restrict__ in_seq,
    const unsigned short* __restrict__ wt,
    const float* __restrict__ be1, const float* __restrict__ be2,
    const float* __restrict__ be3,
    const unsigned short* __restrict__ Wd1t,
    const unsigned short* __restrict__ Wd2t,
    const float* __restrict__ bd1, const float* __restrict__ bd2,
    unsigned short* __restrict__ xseq,
    float* __restrict__ outr)
{
  __shared__ __attribute__((aligned(16))) unsigned short sH[128 * 512];  // 128 KB
  unsigned short* sA = sH;   // alias: input tile (128x128) in sH's head

  const int tid = threadIdx.x;
  const int m0 = blockIdx.x * 128;
  const int wave = tid >> 6, lane = tid & 63;
  const int wm = wave >> 3, wn = wave & 7;
  const int rb = wm << 6;                    // wave's row base (0 or 64)
  const int lrow = lane & 15, lhi = lane >> 4, sw = lrow & 7;

  // stage input tile f32 -> bf16, chunk-swizzled (128 rows x 16 chunks)
#pragma unroll
  for (int p = 0; p < 2; ++p) {
    int id = (p << 10) + tid;
    int row = id >> 4, cc = id & 15;
    const float* src = in_seq + (size_t)(m0 + row) * IN_D + (cc << 3);
    float4v u0 = *(const float4v*)src;
    float4v u1 = *(const float4v*)(src + 4);
    u16x8 h;
    h[0] = f2bf(u0[0]); h[1] = f2bf(u0[1]); h[2] = f2bf(u0[2]); h[3] = f2bf(u0[3]);
    h[4] = f2bf(u1[0]); h[5] = f2bf(u1[1]); h[6] = f2bf(u1[2]); h[7] = f2bf(u1[3]);
    int slot = (cc & 8) | ((cc & 7) ^ (row & 7));
    *(u16x8*)(sA + (row << 7) + (slot << 3)) = h;
  }
  __syncthreads();

  f32x4 acc[4][4];
  const unsigned short* Bts[3] = {wt, wt + 65536, wt + 327680};
  const float* bss[3] = {be1, be2, be3};

  // ---- 3 encoder layers (in-place in sH) ----
  for (int l = 0; l < 3; ++l) {
    const int lstr = (l == 0) ? 128 : 512;
    const int nk = (l == 0) ? 4 : 16;
    const unsigned short* bl = Bts[l] + (lane << 3);
    const int nfb = (wn << 2) * nk;
    const float* bias = bss[l];

#pragma unroll
    for (int m = 0; m < 4; ++m)
#pragma unroll
      for (int n = 0; n < 4; ++n) acc[m][n] = (f32x4){0.f, 0.f, 0.f, 0.f};

    bf16x8 b0[4], b1[4];
#pragma unroll
    for (int n = 0; n < 4; ++n)
      b0[n] = *(const bf16x8*)(bl + ((nfb + n * nk) << 9));

    for (int kk = 0; kk < nk; kk += 2) {
#pragma unroll
      for (int n = 0; n < 4; ++n)
        b1[n] = *(const bf16x8*)(bl + ((nfb + n * nk + kk + 1) << 9));
      {
        const int c = (kk << 2) + lhi;
        const int slot = (c & ~7) | ((c & 7) ^ sw);
        bf16x8 af[4];
#pragma unroll
        for (int m = 0; m < 4; ++m)
          af[m] = *(const bf16x8*)(sH + (rb + m * 16 + lrow) * lstr + (slot << 3));
#pragma unroll
        for (int n = 0; n < 4; ++n)
#pragma unroll
          for (int m = 0; m < 4; ++m)
            acc[m][n] = MFMA(b0[n], af[m], acc[m][n]);
      }
      if (kk + 2 < nk) {
#pragma unroll
        for (int n = 0; n < 4; ++n)
          b0[n] = *(const bf16x8*)(bl + ((nfb + n * nk + kk + 2) << 9));
      }
      {
        const int c = ((kk + 1) << 2) + lhi;
        const int slot = (c & ~7) | ((c & 7) ^ sw);
        bf16x8 af[4];
#pragma unroll
        for (int m = 0; m < 4; ++m)
          af[m] = *(const bf16x8*)(sH + (rb + m * 16 + lrow) * lstr + (slot << 3));
#pragma unroll
        for (int n = 0; n < 4; ++n)
#pragma unroll
          for (int m = 0; m < 4; ++m)
            acc[m][n] = MFMA(b1[n], af[m], acc[m][n]);
      }
    }
    __syncthreads();
    // epilogue: acc[m][n][q] = D[row=rb+m*16+lrow][col=wn*64+n*16+lhi*4+q]
#pragma unroll
    for (int n = 0; n < 4; ++n) {
      const int col0 = (wn << 6) + n * 16 + (lhi << 2);
      const float4v bv = *(const float4v*)(bias + col0);
      const int c2 = col0 >> 3;
#pragma unroll
      for (int m = 0; m < 4; ++m) {
        const int row = rb + m * 16 + lrow;
        const int slot2 = (c2 & ~7) | ((c2 & 7) ^ (row & 7));
        u16x4 h;
#pragma unroll
        for (int q = 0; q < 4; ++q) h[q] = f2bf(fast_tanh(acc[m][n][q] + bv[q]));
        *(u16x4*)(sH + (row << 9) + (slot2 << 3) + (col0 & 7)) = h;
      }
    }
    __syncthreads();
  }

  // ---- dump xseq (coalesced un-swizzle; read-only on sH) ----
#pragma unroll
  for (int p = 0; p < 8; ++p) {
    int id = (p << 10) + tid;
    int row = id >> 6, cc = id & 63;
    int slot = (cc & ~7) | ((cc & 7) ^ (row & 7));
    u16x8 v = *(const u16x8*)(sH + (row << 9) + (slot << 3));
    *(u16x8*)(xseq + ((size_t)(m0 + row) << 9) + (cc << 3)) = v;
  }

  // ---- recon decoder layer 1 (reads sH-as-X, writes sH-as-d1 in place) ----
#pragma unroll
  for (int m = 0; m < 4; ++m)
#pragma unroll
    for (int n = 0; n < 4; ++n) acc[m][n] = (f32x4){0.f, 0.f, 0.f, 0.f};

  {
    const unsigned short* bl = Wd1t + (lane << 3);
    const int nfb = (wn << 2) << 4;
    bf16x8 b0[4], b1[4];
#pragma unroll
    for (int n = 0; n < 4; ++n)
      b0[n] = *(const bf16x8*)(bl + ((nfb + (n << 4)) << 9));
    for (int kk = 0; kk < 16; kk += 2) {
#pragma unroll
      for (int n = 0; n < 4; ++n)
        b1[n] = *(const bf16x8*)(bl + ((nfb + (n << 4) + kk + 1) << 9));
      {
        const int c = (kk << 2) + lhi;
        const int slot = (c & ~7) | ((c & 7) ^ sw);
        bf16x8 af[4];
#pragma unroll
        for (int m = 0; m < 4; ++m)
          af[m] = *(const bf16x8*)(sH + ((rb + m * 16 + lrow) << 9) + (slot << 3));
#pragma unroll
        for (int n = 0; n < 4; ++n)
#pragma unroll
          for (int m = 0; m < 4; ++m)
            acc[m][n] = MFMA(b0[n], af[m], acc[m][n]);
      }
      if (kk + 2 < 16) {
#pragma unroll
        for (int n = 0; n < 4; ++n)
          b0[n] = *(const bf16x8*)(bl + ((nfb + (n << 4) + kk + 2) << 9));
      }
      {
        const int c = ((kk + 1) << 2) + lhi;
        const int slot = (c & ~7) | ((c & 7) ^ sw);
        bf16x8 af[4];
#pragma unroll
        for (int m = 0; m < 4; ++m)
          af[m] = *(const bf16x8*)(sH + ((rb + m * 16 + lrow) << 9) + (slot << 3));
#pragma unroll
        for (int n = 0; n < 4; ++n)
#pragma unroll
          for (int m = 0; m < 4; ++m)
            acc[m][n] = MFMA(b1[n], af[m], acc[m][n]);
      }
    }
  }
  __syncthreads();   // all sH(X) reads + dump reads done -> overwrite as d1
#pragma unroll
  for (int n = 0; n < 4; ++n) {
    const int col0 = (wn << 6) + n * 16 + (lhi << 2);
    const float4v bv = *(const float4v*)(bd1 + col0);
    const int c2 = col0 >> 3;
#pragma unroll
    for (int m = 0; m < 4; ++m) {
      const int row = rb + m * 16 + lrow;
      const int slot2 = (c2 & ~7) | ((c2 & 7) ^ (row & 7));
      u16x4 h;
#pragma unroll
      for (int q = 0; q < 4; ++q) h[q] = f2bf(fast_tanh(acc[m][n][q] + bv[q]));
      *(u16x4*)(sH + (row << 9) + (slot2 << 3) + (col0 & 7)) = h;
    }
  }
  __syncthreads();

  // ---- recon decoder layer 2: N=128, wave owns one 16-col frag (nf=wn) ----
  f32x4 acc2[4];
#pragma unroll
  for (int m = 0; m < 4; ++m) acc2[m] = (f32x4){0.f, 0.f, 0.f, 0.f};

  {
    const unsigned short* bl = Wd2t + (lane << 3);
    const int nfb = wn << 4;
    bf16x8 c0, c1;
    c0 = *(const bf16x8*)(bl + ((nfb + 0) << 9));
    for (int kk = 0; kk < 16; kk += 2) {
      c1 = *(const bf16x8*)(bl + ((nfb + kk + 1) << 9));
      {
        const int c = (kk << 2) + lhi;
        const int slot = (c & ~7) | ((c & 7) ^ sw);
#pragma unroll
        for (int m = 0; m < 4; ++m) {
          bf16x8 af = *(const bf16x8*)(sH + ((rb + m * 16 + lrow) << 9) + (slot << 3));
          acc2[m] = MFMA(c0, af, acc2[m]);
        }
      }
      if (kk + 2 < 16)
        c0 = *(const bf16x8*)(bl + ((nfb + kk + 2) << 9));
      {
        const int c = ((kk + 1) << 2) + lhi;
        const int slot = (c & ~7) | ((c & 7) ^ sw);
#pragma unroll
        for (int m = 0; m < 4; ++m) {
          bf16x8 af = *(const bf16x8*)(sH + ((rb + m * 16 + lrow) << 9) + (slot << 3));
          acc2[m] = MFMA(c1, af, acc2[m]);
        }
      }
    }
  }
  {
    const int col0 = (wn << 4) + (lhi << 2);
    const float4v bv = *(const float4v*)(bd2 + col0);
#pragma unroll
    for (int m = 0; m < 4; ++m) {
      const int row = rb + m * 16 + lrow;
      float4v o;
#pragma unroll
      for (int q = 0; q < 4; ++q) o[q] = fast_tanh(acc2[m][q] + bv[q]);
      *(float4v*)(outr + (size_t)(m0 + row) * IN_D + col0) = o;
    }
  }
}

// ---------------------------------------------------------------------------
// Fused 2-layer decoder (pred pass). 1024 thr = 16 waves, 128 rows/block.
// ---------------------------------------------------------------------------
__global__ __launch_bounds__(1024) void dec_fused_k(
    const unsigned short* __restrict__ X,
    const unsigned short* __restrict__ Wd1t,
    const unsigned short* __restrict__ Wd2t,
    const float* __restrict__ bd1, const float* __restrict__ bd2,
    float* __restrict__ out)
{
  __shared__ __attribute__((aligned(16))) unsigned short sH[128 * 512];  // 128 KB
  unsigned short* sX = sH;

  const int tid = threadIdx.x;
  const int m0 = blockIdx.x * 128;
  const int wave = tid >> 6, lane = tid & 63;
  const int wm = wave >> 3, wn = wave & 7;
  const int rb = wm << 6;
  const int lrow = lane & 15, lhi = lane >> 4, sw = lrow & 7;

  char* lX = (char*)sX + tid * 16;
#pragma unroll
  for (int p = 0; p < 8; ++p) {
    int id = (p << 10) + tid;
    int row = id >> 6, cc = id & 63;
    int gcc = (cc & ~7) | ((cc & 7) ^ (row & 7));
    gload_lds16(X + ((size_t)(m0 + row) << 9) + (gcc << 3), lX + (p << 14));
  }
  __syncthreads();

  f32x4 acc[4][4];
#pragma unroll
  for (int m = 0; m < 4; ++m)
#pragma unroll
    for (int n = 0; n < 4; ++n) acc[m][n] = (f32x4){0.f, 0.f, 0.f, 0.f};

  {
    const unsigned short* bl = Wd1t + (lane << 3);
    const int nfb = (wn << 2) << 4;
    bf16x8 b0[4], b1[4];
#pragma unroll
    for (int n = 0; n < 4; ++n)
      b0[n] = *(const bf16x8*)(bl + ((nfb + (n << 4)) << 9));
    for (int kk = 0; kk < 16; kk += 2) {
#pragma unroll
      for (int n = 0; n < 4; ++n)
        b1[n] = *(const bf16x8*)(bl + ((nfb + (n << 4) + kk + 1) << 9));
      {
        const int c = (kk << 2) + lhi;
        const int slot = (c & ~7) | ((c & 7) ^ sw);
        bf16x8 af[4];
#pragma unroll
        for (int m = 0; m < 4; ++m)
          af[m] = *(const bf16x8*)(sX + ((rb + m * 16 + lrow) << 9) + (slot << 3));
#pragma unroll
        for (int n = 0; n < 4; ++n)
#pragma unroll
          for (int m = 0; m < 4; ++m)
            acc[m][n] = MFMA(b0[n], af[m], acc[m][n]);
      }
      if (kk + 2 < 16) {
#pragma unroll
        for (int n = 0; n < 4; ++n)
          b0[n] = *(const bf16x8*)(bl + ((nfb + (n << 4) + kk + 2) << 9));
      }
      {
        const int c = ((kk + 1) << 2) + lhi;
        const int slot = (c & ~7) | ((c & 7) ^ sw);
        bf16x8 af[4];
#pragma unroll
        for (int m = 0; m < 4; ++m)
          af[m] = *(const bf16x8*)(sX + ((rb + m * 16 + lrow) << 9) + (slot << 3));
#pragma unroll
        for (int n = 0; n < 4; ++n)
#pragma unroll
          for (int m = 0; m < 4; ++m)
            acc[m][n] = MFMA(b1[n], af[m], acc[m][n]);
      }
    }
  }
  __syncthreads();
#pragma unroll
  for (int n = 0; n < 4; ++n) {
    const int col0 = (wn << 6) + n * 16 + (lhi << 2);
    const float4v bv = *(const float4v*)(bd1 + col0);
    const int c2 = col0 >> 3;
#pragma unroll
    for (int m = 0; m < 4; ++m) {
      const int row = rb + m * 16 + lrow;
      const int slot2 = (c2 & ~7) | ((c2 & 7) ^ (row & 7));
      u16x4 h;
#pragma unroll
      for (int q = 0; q < 4; ++q) h[q] = f2bf(fast_tanh(acc[m][n][q] + bv[q]));
      *(u16x4*)(sH + (row << 9) + (slot2 << 3) + (col0 & 7)) = h;
    }
  }
  __syncthreads();

  f32x4 acc2[4];
#pragma unroll
  for (int m = 0; m < 4; ++m) acc2[m] = (f32x4){0.f, 0.f, 0.f, 0.f};

  {
    const unsigned short* bl = Wd2t + (lane << 3);
    const int nfb = wn << 4;
    bf16x8 c0, c1;
    c0 = *(const bf16x8*)(bl + ((nfb + 0) << 9));
    for (int kk = 0; kk < 16; kk += 2) {
      c1 = *(const bf16x8*)(bl + ((nfb + kk + 1) << 9));
      {
        const int c = (kk << 2) + lhi;
        const int slot = (c & ~7) | ((c & 7) ^ sw);
#pragma unroll
        for (int m = 0; m < 4; ++m) {
          bf16x8 af = *(const bf16x8*)(sH + ((rb + m * 16 + lrow) << 9) + (slot << 3));
          acc2[m] = MFMA(c0, af, acc2[m]);
        }
      }
      if (kk + 2 < 16)
        c0 = *(const bf16x8*)(bl + ((nfb + kk + 2) << 9));
      {
        const int c = ((kk + 1) << 2) + lhi;
        const int slot = (c & ~7) | ((c & 7) ^ sw);
#pragma unroll
        for (int m = 0; m < 4; ++m) {
          bf16x8 af = *(const bf16x8*)(sH + ((rb + m * 16 + lrow) << 9) + (slot << 3));
          acc2[m] = MFMA(c1, af, acc2[m]);
        }
      }
    }
  }
  {
    const int col0 = (wn << 4) + (lhi << 2);
    const float4v bv = *(const float4v*)(bd2 + col0);
#pragma unroll
    for (int m = 0; m < 4; ++m) {
      const int row = rb + m * 16 + lrow;
      float4v o;
#pragma unroll
      for (int q = 0; q < 4; ++q) o[q] = fast_tanh(acc2[m][q] + bv[q]);
      *(float4v*)(out + (size_t)(m0 + row) * IN_D + col0) = o;
    }
  }
}

// ---------------------------------------------------------------------------
// rec_all: ALL 5 recurrence steps in one kernel. Block = one chain (32 rows).
// (proven round-13 version, 512 threads)
// ---------------------------------------------------------------------------
__global__ __launch_bounds__(512) void rec_all_k(
    const unsigned short* __restrict__ Wrec,
    unsigned short* __restrict__ xsall)   // in: xseq rows at t0; out: pred states
{
  __shared__ float xst[32][516];                                        // 64.5 KB
  __shared__ __attribute__((aligned(16))) unsigned short sA[32 * 512];  // 32 KB

  const int tid = threadIdx.x;
  const int chain = blockIdx.x;
  const int t0 = chain * 5;
  const int wave = tid >> 6, lane = tid & 63;
  const int wn = wave;
  const int lrow = lane & 15, lhi = lane >> 4, sw = lrow & 7;

  // coalesced init: xsall[row, t0, :] bf16 -> xst f32
#pragma unroll
  for (int p = 0; p < 4; ++p) {
    int id = (p << 9) + tid;
    int row = id >> 6, c8 = (id & 63) << 3;
    u16x8 v = *(const u16x8*)(xsall + (((size_t)row * T_SZ + t0) << 9) + c8);
#pragma unroll
    for (int e = 0; e < 8; ++e) xst[row][c8 + e] = bf2f(v[e]);
  }
  __syncthreads();

  const unsigned short* bl = Wrec + (lane << 3);
  const int nfb = (wn << 2) << 4;

  for (int s = 0; s < 5; ++s) {
    // stage tanh(xst) -> sA (swizzled)
#pragma unroll
    for (int p = 0; p < 4; ++p) {
      int id = (p << 9) + tid;
      int row = id >> 6, cc = id & 63;
      int gc = (cc & ~7) | ((cc & 7) ^ (row & 7));
      const float* src = &xst[row][gc << 3];
      float4v u0 = *(const float4v*)src;
      float4v u1 = *(const float4v*)(src + 4);
      u16x8 h;
      h[0] = f2bf(fast_tanh(u0[0])); h[1] = f2bf(fast_tanh(u0[1]));
      h[2] = f2bf(fast_tanh(u0[2])); h[3] = f2bf(fast_tanh(u0[3]));
      h[4] = f2bf(fast_tanh(u1[0])); h[5] = f2bf(fast_tanh(u1[1]));
      h[6] = f2bf(fast_tanh(u1[2])); h[7] = f2bf(fast_tanh(u1[3]));
      *(u16x8*)(sA + (row << 9) + (cc << 3)) = h;
    }
    __syncthreads();

    f32x4 acc[2][4];
#pragma unroll
    for (int m = 0; m < 2; ++m)
#pragma unroll
      for (int n = 0; n < 4; ++n) acc[m][n] = (f32x4){0.f, 0.f, 0.f, 0.f};

    bf16x8 b0[4], b1[4];
#pragma unroll
    for (int n = 0; n < 4; ++n)
      b0[n] = *(const bf16x8*)(bl + ((nfb + (n << 4)) << 9));
    for (int kk = 0; kk < 16; kk += 2) {
#pragma unroll
      for (int n = 0; n < 4; ++n)
        b1[n] = *(const bf16x8*)(bl + ((nfb + (n << 4) + kk + 1) << 9));
      {
        const int c = (kk << 2) + lhi;
        const int slot = (c & ~7) | ((c & 7) ^ sw);
        bf16x8 af0 = *(const bf16x8*)(sA + (lrow << 9) + (slot << 3));
        bf16x8 af1 = *(const bf16x8*)(sA + ((16 + lrow) << 9) + (slot << 3));
#pragma unroll
        for (int n = 0; n < 4; ++n) {
          acc[0][n] = MFMA(b0[n], af0, acc[0][n]);
          acc[1][n] = MFMA(b0[n], af1, acc[1][n]);
        }
      }
      if (kk + 2 < 16) {
#pragma unroll
        for (int n = 0; n < 4; ++n)
          b0[n] = *(const bf16x8*)(bl + ((nfb + (n << 4) + kk + 2) << 9));
      }
      {
        const int c = ((kk + 1) << 2) + lhi;
        const int slot = (c & ~7) | ((c & 7) ^ sw);
        bf16x8 af0 = *(const bf16x8*)(sA + (lrow << 9) + (slot << 3));
        bf16x8 af1 = *(const bf16x8*)(sA + ((16 + lrow) << 9) + (slot << 3));
#pragma unroll
        for (int n = 0; n < 4; ++n) {
          acc[0][n] = MFMA(b1[n], af0, acc[0][n]);
          acc[1][n] = MFMA(b1[n], af1, acc[1][n]);
        }
      }
    }
    __syncthreads();   // all staging/k-loop reads of xst & sA complete

    // epilogue: update xst in place + write pred state at t = t0 + s
    const int t = t0 + s;
#pragma unroll
    for (int n = 0; n < 4; ++n) {
      const int col0 = (wn << 6) + n * 16 + (lhi << 2);
#pragma unroll
      for (int m = 0; m < 2; ++m) {
        const int row = m * 16 + lrow;
        float4v x = *(const float4v*)(&xst[row][col0]);
        float4v xn;
#pragma unroll
        for (int q = 0; q < 4; ++q) xn[q] = x[q] + (acc[m][n][q] - x[q]) * INV_TAUX;
        *(float4v*)(&xst[row][col0]) = xn;
        if (t < T_SZ) {
          u16x4 h;
#pragma unroll
          for (int q = 0; q < 4; ++q) h[q] = f2bf(xn[q]);
          *(u16x4*)(xsall + ((size_t)row * T_SZ + t) * HID + col0) = h;
        }
      }
    }
    __syncthreads();   // xst updates visible before next step's staging
  }
}

// weight prep into fragment-linear layout:
// flat[((nf*nk+kk)*64+lane)*8+e] = B[nf*16+(lane&15)][kk*32+(lane>>4)*8+e]
__global__ void prep_k(const float* __restrict__ We1, const float* __restrict__ We2,
                       const float* __restrict__ We3, const float* __restrict__ Wd1,
                       const float* __restrict__ Wd2, const float* __restrict__ W,
                       unsigned short* __restrict__ wt) {
  int idx = blockIdx.x * blockDim.x + threadIdx.x;
  if (idx >= 1179648) return;
  unsigned short v;
  if (idx < 65536) {
    int i = idx, lane = (i >> 3) & 63, t2 = i >> 9;
    int kk = t2 & 3, nf = t2 >> 2;
    int n = (nf << 4) + (lane & 15), k = (kk << 5) + ((lane >> 4) << 3) + (i & 7);
    v = f2bf(We1[k * 512 + n]);
  } else if (idx < 327680) {
    int i = idx - 65536, lane = (i >> 3) & 63, t2 = i >> 9;
    int kk = t2 & 15, nf = t2 >> 4;
    int n = (nf << 4) + (lane & 15), k = (kk << 5) + ((lane >> 4) << 3) + (i & 7);
    v = f2bf(We2[k * 512 + n]);
  } else if (idx < 589824) {
    int i = idx - 327680, lane = (i >> 3) & 63, t2 = i >> 9;
    int kk = t2 & 15, nf = t2 >> 4;
    int n = (nf << 4) + (lane & 15), k = (kk << 5) + ((lane >> 4) << 3) + (i & 7);
    v = f2bf(We3[k * 512 + n]);
  } else if (idx < 851968) {
    int i = idx - 589824, lane = (i >> 3) & 63, t2 = i >> 9;
    int kk = t2 & 15, nf = t2 >> 4;
    int n = (nf << 4) + (lane & 15), k = (kk << 5) + ((lane >> 4) << 3) + (i & 7);
    v = f2bf(Wd1[k * 512 + n]);
  } else if (idx < 917504) {
    int i = idx - 851968, lane = (i >> 3) & 63, t2 = i >> 9;
    int kk = t2 & 15, nf = t2 >> 4;
    int n = (nf << 4) + (lane & 15), k = (kk << 5) + ((lane >> 4) << 3) + (i & 7);
    v = f2bf(Wd2[k * 128 + n]);
  } else {
    int i = idx - 917504, lane = (i >> 3) & 63, t2 = i >> 9;
    int kk = t2 & 15, nf = t2 >> 4;
    int n = (nf << 4) + (lane & 15), k = (kk << 5) + ((lane >> 4) << 3) + (i & 7);
    v = f2bf(W[(n << 9) + k]);
  }
  wt[idx] = v;
}

__global__ void sentinel_k(float* out, float v) { out[0] = v; }

extern "C" void kernel_launch(void* const* d_in, const int* in_sizes, int n_in,
                              void* d_out, int out_size, void* d_ws, size_t ws_size,
                              hipStream_t stream) {
  const float* in_seq = (const float*)d_in[0];
  const float* We1 = (const float*)d_in[1];
  const float* be1 = (const float*)d_in[2];
  const float* We2 = (const float*)d_in[3];
  const float* be2 = (const float*)d_in[4];
  const float* We3 = (const float*)d_in[5];
  const float* be3 = (const float*)d_in[6];
  const float* Wd1 = (const float*)d_in[7];
  const float* bd1 = (const float*)d_in[8];
  const float* Wd2 = (const float*)d_in[9];
  const float* bd2 = (const float*)d_in[10];
  const float* W   = (const float*)d_in[11];

  const int NROW = B_SZ * T_SZ;                       // 65536
  const size_t OFF_XSEQ = 0;                          // 67,108,864 B
  const size_t OFF_WT   = (size_t)NROW * HID * 2;     // 67,108,864
  const size_t REQUIRED = OFF_WT + 2359296;           // 69,468,160

  float* outp = (float*)d_out;
  float* outr = outp + (size_t)NROW * IN_D;

  if (ws_size < REQUIRED) {
    sentinel_k<<<1, 1, 0, stream>>>(outp, (float)(ws_size >> 20));
    return;
  }

  char* ws = (char*)d_ws;
  unsigned short* xseq = (unsigned short*)(ws + OFF_XSEQ);  // reused as xsall
  unsigned short* wt   = (unsigned short*)(ws + OFF_WT);
  unsigned short* Wd1t = wt + 589824;
  unsigned short* Wd2t = wt + 851968;
  unsigned short* Wrec = wt + 917504;

  prep_k<<<4608, 256, 0, stream>>>(We1, We2, We3, Wd1, Wd2, W, wt);
  enc5_k<<<512, 1024, 0, stream>>>(in_seq, wt, be1, be2, be3,
                                   Wd1t, Wd2t, bd1, bd2, xseq, outr);
  rec_all_k<<<NCHAIN, 512, 0, stream>>>(Wrec, xseq);
  dec_fused_k<<<512, 1024, 0, stream>>>(xseq, Wd1t, Wd2t, bd1, bd2, outp);
}